// Round 13
// baseline (571.157 us; speedup 1.0000x reference)
//
#include <hip/hip_runtime.h>
#include <hip/hip_bf16.h>
#include <stdint.h>

// ---- problem constants ----
#define NB   65536      // batch points
#define NC   2
#define NV   3
#define ND   64
#define NK   1024       // codebook entries
#define NS   4
#define NH   1024
#define NL   5
#define NF   25
#define NIN  102
#define K0P  128        // padded layer-0 K

typedef float f32x4 __attribute__((ext_vector_type(4)));
typedef int   i32x4 __attribute__((ext_vector_type(4)));
typedef int   i32x8 __attribute__((ext_vector_type(8)));
typedef unsigned char u8;
typedef unsigned short u16;
typedef unsigned int u32;

__device__ __forceinline__ void load_lds16(const void* g, void* l) {
    __builtin_amdgcn_global_load_lds(
        (const __attribute__((address_space(1))) void*)g,
        (__attribute__((address_space(3))) void*)l,
        16, 0, 0);
}

// fp32 -> fp4 e2m1 nibble (sign|e2m1), grid {0,.5,1,1.5,2,3,4,6}, RNE-ish.
// Input is PRE-SCALED; the e8m0 MFMA scale undoes the pre-scale exactly.
__device__ __forceinline__ u32 to_fp4(float x) {
    float ax = fabsf(x);
    u32 s = (x < 0.0f) ? 8u : 0u;
    u32 m;
    if      (ax < 0.25f) m = 0;   // 0
    else if (ax < 0.75f) m = 1;   // 0.5
    else if (ax < 1.25f) m = 2;   // 1
    else if (ax < 1.75f) m = 3;   // 1.5
    else if (ax < 2.50f) m = 4;   // 2
    else if (ax < 3.50f) m = 5;   // 3
    else if (ax < 5.00f) m = 6;   // 4
    else                 m = 7;   // 6
    return s | m;
}

// ===========================================================================
// FP4 TILED OPERAND LAYOUTS (R13) — nibble-packed, fragment-order storage.
//  W_t: byte = (((bn*nIt + it)*8 + j)*64 + q*16 + r16)*16 + (koff>>1)
//       holds W[n][k]: n = bn*128+j*16+r16, k = it*128 + q*32 + koff.
//       Per-(bn,it) slab = 8 KB contiguous (LDS double-buffer staging).
//  A_t: byte = ((m16*(K/32) + c32)*16 + r)*16 + (koff>>1)
//       holds A[m][k]: m = m16*16+r, k = c32*32 + koff. Direct-global frags.
//  Byte b holds k-elems {2b (low nibble), 2b+1 (high)} — consistent A/W
//  convention => any HW-internal k order cancels in the dot product.
// ===========================================================================

// ---------------------------------------------------------------------------
// VQ kernel: single block, 1024 threads. Exact fp32 (idx/loss thresholds are
// the tight ones — untouched).
// ---------------------------------------------------------------------------
__global__ __launch_bounds__(1024) void vq_kernel(
    const float* __restrict__ latents, const int* __restrict__ latent_idx,
    const float* __restrict__ codebooks, float* __restrict__ zq_out,
    float* __restrict__ out) {
    __shared__ float zcur[ND], resid[ND], zqsum[ND], ssq[ND];
    __shared__ float sDw[16];
    __shared__ int   sKw[16];
    __shared__ int   sBest;
    int t = threadIdx.x, lane = t & 63, wv = t >> 6;
    const float* img = latents + (size_t)latent_idx[0] * (NS * ND);
    if (t < ND) { resid[t] = 0.f; zqsum[t] = 0.f; }
    __syncthreads();
    float lossAcc = 0.f;   // thread 0 only
    for (int s = 0; s < NS; s++) {
        if (t < ND) {
            float iv = img[s * ND + t];
            float r  = resid[t] + iv;
            resid[t] = r;
            zcur[t]  = (s == 0) ? iv : (r - zqsum[t]);
        }
        __syncthreads();
        float zz = 0.f;
#pragma unroll
        for (int d = 0; d < ND; d++) { float z = zcur[d]; zz += z * z; }
        const float4* e4 = (const float4*)(codebooks + ((size_t)s * NK + t) * ND);
        float dot = 0.f, ee = 0.f;
#pragma unroll
        for (int i = 0; i < 16; i++) {
            float4 v = e4[i];
            dot += zcur[4 * i + 0] * v.x; dot += zcur[4 * i + 1] * v.y;
            dot += zcur[4 * i + 2] * v.z; dot += zcur[4 * i + 3] * v.w;
            ee  += v.x * v.x; ee += v.y * v.y; ee += v.z * v.z; ee += v.w * v.w;
        }
        float dmin = zz - 2.0f * dot + ee;
        int   kmin = t;
#pragma unroll
        for (int m = 1; m < 64; m <<= 1) {
            float d2 = __shfl_xor(dmin, m);
            int   k2 = __shfl_xor(kmin, m);
            if (d2 < dmin || (d2 == dmin && k2 < kmin)) { dmin = d2; kmin = k2; }
        }
        if (lane == 0) { sDw[wv] = dmin; sKw[wv] = kmin; }
        __syncthreads();
        if (t == 0) {
            float bd = sDw[0]; int bk = sKw[0];
            for (int w = 1; w < 16; w++) {
                float d2 = sDw[w]; int k2 = sKw[w];
                if (d2 < bd || (d2 == bd && k2 < bk)) { bd = d2; bk = k2; }
            }
            sBest = bk;
            out[NB * NV + s] = (float)bk;
        }
        __syncthreads();
        int best = sBest;
        const float* eb = codebooks + ((size_t)s * NK + best) * ND;
        if (t < ND) {
            float zq = eb[t];
            float d  = zq - zcur[t];
            ssq[t]   = d * d;
            zqsum[t] = zqsum[t] + (zq + (zcur[t] - zq));   // z_q_st forward (exact ref arith)
        }
        __syncthreads();
        if (t == 0) {
            float sum = 0.f;
            for (int d = 0; d < ND; d++) sum += ssq[d];
            lossAcc += 0.25f * (sum / (float)ND);
        }
    }
    if (t < ND) zq_out[t] = zqsum[t];
    if (t == 0) out[NB * NV + NS] = lossAcc;
}

// ---------------------------------------------------------------------------
// betas fused with decoder biases (fp32)
// ---------------------------------------------------------------------------
__global__ __launch_bounds__(256) void betas_kernel(
    const float* __restrict__ zq, const float* __restrict__ mod_W,
    const float* __restrict__ mod_b, const float* __restrict__ b0,
    const float* __restrict__ bh, float* __restrict__ bb) {
    int g = blockIdx.x * 256 + threadIdx.x;   // < 5120
    int l = g >> 10, n = g & 1023;
    float acc = mod_b[g];
    for (int d = 0; d < ND; d++) acc += zq[d] * mod_W[(size_t)(l * ND + d) * NH + n];
    acc += (l == 0) ? b0[n] : bh[(size_t)(l - 1) * NH + n];
    bb[g] = acc;
}

// ---------------------------------------------------------------------------
// out init: values[m][v] = bout[v] (atomic-add target for the fused layer)
// ---------------------------------------------------------------------------
__global__ __launch_bounds__(256) void init_out_kernel(
    const float* __restrict__ bout, float* __restrict__ out) {
    int g = blockIdx.x * 256 + threadIdx.x;   // < NB*NV
    out[g] = bout[g % NV];
}

// ---------------------------------------------------------------------------
// Weight prep: fp32 [Ks][1024] -> fp4 W_t (value * presc quantized to e2m1;
// presc undone exactly by the e8m0 MFMA scale). Zero-pad k>=Ks.
// ---------------------------------------------------------------------------
__global__ __launch_bounds__(256) void prep_kernel(
    const float* __restrict__ src, u8* __restrict__ dst, int Ks, int Kp,
    float presc) {
    __shared__ float tile[32][33];
    int nIt = Kp >> 7;
    src += (size_t)blockIdx.z * Ks * NH;
    dst += (size_t)blockIdx.z * NH * (Kp >> 1);
    int k0 = blockIdx.x * 32, n0 = blockIdx.y * 32;
    int tx = threadIdx.x & 31, ty = threadIdx.x >> 5;   // (32, 8)
    for (int i = 0; i < 4; i++) {
        int k = k0 + ty + i * 8;
        int n = n0 + tx;
        tile[ty + i * 8][tx] = (k < Ks) ? src[(size_t)k * NH + n] : 0.0f;
    }
    __syncthreads();
    // each thread: one n, 4 consecutive k -> one ushort (2 bytes, 4 nibbles)
    int tid = threadIdx.x;
    int n   = n0 + (tid >> 3);
    int ks  = (tid & 7) * 4;              // k offset within the 32-block
    u32 n0b = to_fp4(tile[ks + 0][n - n0] * presc);
    u32 n1b = to_fp4(tile[ks + 1][n - n0] * presc);
    u32 n2b = to_fp4(tile[ks + 2][n - n0] * presc);
    u32 n3b = to_fp4(tile[ks + 3][n - n0] * presc);
    u16 us = (u16)((n0b | (n1b << 4)) | ((n2b | (n3b << 4)) << 8));
    int it = k0 >> 7, q = (k0 >> 5) & 3;
    int bn = n >> 7, j = (n >> 4) & 7, r16 = n & 15;
    size_t flat = ((size_t)(((bn * nIt + it) * 8 + j) * 64 + q * 16 + r16)) * 16 + (ks >> 1);
    *(u16*)(dst + flat) = us;
}

// ---------------------------------------------------------------------------
// Positional encoding -> fp4 A_t [Bc][128] (K/32 = 4 chunks). presc = 4
// (scale byte 125 = 2^-2). |pe| <= 1 -> max stored 4 < 6, res 0.125.
// ---------------------------------------------------------------------------
__device__ __forceinline__ float pe_val(const float* coords, int m, int k) {
    if (k < 2) return coords[m * 2 + k];
    if (k >= NIN) return 0.0f;
    int u = k - 2;
    int f = u >> 2, r = u & 3;
    float c = coords[m * 2 + (r & 1)];
    float a = c * __builtin_ldexpf(3.14159274101257324f, f);
    return (r < 2) ? sinf(a) : cosf(a);
}

__global__ __launch_bounds__(256) void pe_kernel(
    const float* __restrict__ coords, u8* __restrict__ pe) {
    int g = blockIdx.x * 256 + threadIdx.x;   // < Bc*16
    int m = g >> 4, k8 = (g & 15) * 8;
    u32 w = 0;
#pragma unroll
    for (int e = 0; e < 8; e++)
        w |= to_fp4(pe_val(coords, m, k8 + e) * 4.0f) << (4 * e);
    // A_t (K=128): dword at ((m16*4 + c32)*16 + r)*16 + (k8>>1)
    int m16 = m >> 4, r = m & 15, c32 = k8 >> 5, b = (k8 & 31) >> 1;
    *(u32*)(pe + ((size_t)(m16 * 4 + c32) * 16 + r) * 16 + b) = w;
}

// ---------------------------------------------------------------------------
// MX-fp4 MFMA GEMM, R13: R12's pipelined structure at fp4 (cbsz=blgp=4).
// 256m x 128n block tile, 4 waves stacked in m, wave tile 64x128
// (acc[4][8] = 128 regs). W via 8KB LDS double-buffer slabs; A via i32x4
// register prefetch. One barrier per iter AFTER the MFMA block. Uniform
// e8m0 scales passed per layer (kwrep/karep = byte * 0x01010101; same
// operand slots as the R8-verified fp8 call).
// MODE 0: relu(acc+bb) * 0.5 -> fp4 (consumed with scale byte 128 = 2^1),
//         repack to next layer's A_t via 16KB LDS, coalesced dwordx4 out.
// MODE 1: out[m][v] += relu(acc+bb).Wout[n][v], q-lane shfl + atomicAdd.
// ---------------------------------------------------------------------------
template <int MODE, int KT>
__global__ __launch_bounds__(256, 2) void gemm_kernel(
    const u8* __restrict__ A, const u8* __restrict__ W,
    const float* __restrict__ bb, u8* __restrict__ O,
    const float* __restrict__ Wout, float* __restrict__ out, int Mb,
    u32 kwrep, u32 karep) {
    __shared__ __align__(16) u8 smem[16384];
    u8* sW0 = smem;              // W buf 0 (8 KB)
    u8* sW1 = smem + 8192;       // W buf 1
    int t   = threadIdx.x;
    int fid = blockIdx.x;
    int xcd = fid & 7;
    int j8  = fid >> 3;                 // 0..Mb-1
    int bn  = j8 & 7;                   // fastest within an XCD
    int bm  = xcd * (Mb >> 3) + (j8 >> 3);
    int lane = t & 63, wm = t >> 6;     // wave owns m-slice wm*64..+63
    int q    = lane >> 4, r16 = lane & 15;
    const int nIt = KT >> 7;

    const u8* wslab = W + (size_t)(bn * nIt) * 8192;
    const u8* abase = A + (size_t)(bm * 16 + wm * 4) * (KT >> 5) * 256
                        + (size_t)q * 256 + r16 * 16;

    f32x4 acc[4][8];
    f32x4 zero = {0.f, 0.f, 0.f, 0.f};
    for (int i = 0; i < 4; i++)
        for (int j = 0; j < 8; j++) acc[i][j] = zero;

    i32x4 zed = {0, 0, 0, 0};

    // ---- prologue: stage W(it=0) into buf0, load A(it=0) ----
#pragma unroll
    for (int p = 0; p < 2; p++) {
        int g = p * 256 + t;
        load_lds16((const void*)(wslab + g * 16), (void*)(sW0 + g * 16));
    }
    i32x4 afc[4], afn[4];
#pragma unroll
    for (int i = 0; i < 4; i++)
        afc[i] = *(const i32x4*)(abase + (size_t)i * (KT >> 5) * 256);
    __syncthreads();

#pragma unroll 1
    for (int it = 0; it < nIt; it++) {
        u8* bufc = (it & 1) ? sW1 : sW0;
        u8* bufn = (it & 1) ? sW0 : sW1;
        if (it + 1 < nIt) {
            const u8* ws = wslab + (size_t)(it + 1) * 8192;
#pragma unroll
            for (int p = 0; p < 2; p++) {
                int g = p * 256 + t;
                load_lds16((const void*)(ws + g * 16), (void*)(bufn + g * 16));
            }
#pragma unroll
            for (int i = 0; i < 4; i++)
                afn[i] = *(const i32x4*)(abase + ((size_t)i * (KT >> 5) + (it + 1) * 4) * 256);
        }
        // ---- compute with current W buffer + afc ----
#pragma unroll
        for (int j = 0; j < 8; j++) {
            i32x4 wd = *(const i32x4*)(bufc + (j * 64 + lane) * 16);
            i32x8 bfr = __builtin_shufflevector(wd, zed, 0, 1, 2, 3, 4, 5, 6, 7);
#pragma unroll
            for (int i = 0; i < 4; i++) {
                i32x8 af = __builtin_shufflevector(afc[i], zed, 0, 1, 2, 3, 4, 5, 6, 7);
                acc[i][j] = __builtin_amdgcn_mfma_scale_f32_16x16x128_f8f6f4(
                    bfr, af, acc[i][j], 4, 4,      // cbsz=4 (fp4), blgp=4 (fp4)
                    0, (int)kwrep,                 // scale src0 (W)
                    0, (int)karep);                // scale src1 (A)
            }
        }
        __syncthreads();
#pragma unroll
        for (int i = 0; i < 4; i++) afc[i] = afn[i];
    }

    // lane element (i,j,r): m = bm*256+wm*64+i*16+r16, n = bn*128+j*16+q*4+r
    if constexpr (MODE == 0) {
        // Repack to next layer's A_t (K=1024 -> 32 c32-chunks per m16).
        // LDS tile: [(m16_l*4 + c32_l)*16 + r16]*16 B. Lane's 8 vals for
        // (i, b=j>>1) occupy bytes {2q,2q+1} (j=2b) and {8+2q,8+2q+1} (j=2b+1).
        u8* eb = smem;
#pragma unroll
        for (int i = 0; i < 4; i++) {
#pragma unroll
            for (int b = 0; b < 4; b++) {
                u16 us[2];
#pragma unroll
                for (int h = 0; h < 2; h++) {
                    int j  = 2 * b + h;
                    int nl = j * 16 + q * 4;
                    f32x4 b4 = *(const f32x4*)(bb + bn * 128 + nl);
                    u32 n0b = to_fp4(fmaxf(acc[i][j][0] + b4[0], 0.0f) * 0.5f);
                    u32 n1b = to_fp4(fmaxf(acc[i][j][1] + b4[1], 0.0f) * 0.5f);
                    u32 n2b = to_fp4(fmaxf(acc[i][j][2] + b4[2], 0.0f) * 0.5f);
                    u32 n3b = to_fp4(fmaxf(acc[i][j][3] + b4[3], 0.0f) * 0.5f);
                    us[h] = (u16)((n0b | (n1b << 4)) | ((n2b | (n3b << 4)) << 8));
                }
                int rowb = (((wm * 4 + i) * 4 + b) * 16 + r16) * 16;
                *(u16*)(eb + rowb + 2 * q)     = us[0];
                *(u16*)(eb + rowb + 8 + 2 * q) = us[1];
            }
        }
        __syncthreads();
        // 16 KB out: 64 segments (m16_l, c32_l) x 256 B, coalesced dwordx4
#pragma unroll
        for (int rd = 0; rd < 4; rd++) {
            int g2  = rd * 256 + t;            // 16B-chunk index 0..1023
            int seg = g2 >> 4, off = (g2 & 15) * 16;
            int m16l = seg >> 2, c32l = seg & 3;
            i32x4 v = *(const i32x4*)(eb + seg * 256 + off);
            *(i32x4*)(O + ((size_t)((bm * 16 + m16l) * 32 + bn * 4 + c32l)) * 256 + off) = v;
        }
    } else {
#pragma unroll
        for (int i = 0; i < 4; i++) {
            float p0 = 0.f, p1 = 0.f, p2 = 0.f;
#pragma unroll
            for (int j = 0; j < 8; j++) {
                int nb = bn * 128 + j * 16 + q * 4;
                f32x4 b4 = *(const f32x4*)(bb + nb);
#pragma unroll
                for (int r = 0; r < 4; r++) {
                    float val = fmaxf(acc[i][j][r] + b4[r], 0.0f);
                    const float* w = Wout + (size_t)(nb + r) * NV;
                    p0 += val * w[0]; p1 += val * w[1]; p2 += val * w[2];
                }
            }
            p0 += __shfl_xor(p0, 16); p0 += __shfl_xor(p0, 32);
            p1 += __shfl_xor(p1, 16); p1 += __shfl_xor(p1, 32);
            p2 += __shfl_xor(p2, 16); p2 += __shfl_xor(p2, 32);
            if (q == 0) {
                int m = bm * 256 + wm * 64 + i * 16 + r16;
                atomicAdd(&out[(size_t)m * NV + 0], p0);
                atomicAdd(&out[(size_t)m * NV + 1], p1);
                atomicAdd(&out[(size_t)m * NV + 2], p2);
            }
        }
    }
}

// ---------------------------------------------------------------------------
extern "C" void kernel_launch(void* const* d_in, const int* in_sizes, int n_in,
                              void* d_out, int out_size, void* d_ws, size_t ws_size,
                              hipStream_t stream) {
    const float* coords     = (const float*)d_in[0];
    const int*   latent_idx = (const int*)d_in[1];
    const float* latents    = (const float*)d_in[2];
    const float* codebooks  = (const float*)d_in[3];
    const float* mod_W      = (const float*)d_in[4];
    const float* mod_b      = (const float*)d_in[5];
    const float* dec_W0     = (const float*)d_in[6];
    const float* dec_b0     = (const float*)d_in[7];
    const float* dec_Wh     = (const float*)d_in[8];
    const float* dec_bh     = (const float*)d_in[9];
    const float* dec_Wout   = (const float*)d_in[10];
    const float* dec_bout   = (const float*)d_in[11];
    float* out = (float*)d_out;

    // ---- workspace layout (fixed part ~2.2 MB, fp4 weights) ----
    char* wsb = (char*)d_ws;
    float* zq  = (float*)(wsb + 0);                        //      256 B
    float* bb  = (float*)(wsb + 256);                      //   20,480 B
    u8*    W0T = (u8*)(wsb + 20736);                       //   65,536 B  fp4 tiled
    u8*    WhT = (u8*)(wsb + 86272);                       // 2,097,152 B fp4 tiled
    const size_t fixed_end = 2183424;                      // 256-aligned

    // adaptive chunk (fp4 activations: Bc*NH/2 bytes per buffer)
    int Bc = 65536;
    while (Bc > 2048 && fixed_end + (size_t)Bc * NH > ws_size)
        Bc >>= 1;
    int Mb = Bc / 256;   // m-tiles of 256 (multiple of 8 for the XCD decode)

    u8* hA = (u8*)(wsb + fixed_end);                       // [Bc][1024] fp4 A_t
    u8* hB = hA + (size_t)Bc * NH / 2;                     // [Bc][1024] fp4 A_t
    u8* pe = hB;   // pe A_t [Bc][128] fp4 aliases hB (dead before layer 1)

    // e8m0 scale bytes (value = 2^(byte-127)), replicated into all 4 bytes:
    //   Wh x2^5 -> 122; W0 x2^4 -> 123; pe x2^2 -> 125; hidden act x2^-1 -> 128
    const u32 kw_h  = 122u * 0x01010101u;
    const u32 kw_0  = 123u * 0x01010101u;
    const u32 ka_pe = 125u * 0x01010101u;
    const u32 ka_h  = 128u * 0x01010101u;

    // ---- one-time (per call) small kernels ----
    vq_kernel<<<1, 1024, 0, stream>>>(latents, latent_idx, codebooks, zq, out);
    betas_kernel<<<20, 256, 0, stream>>>(zq, mod_W, mod_b, dec_b0, dec_bh, bb);
    init_out_kernel<<<(NB * NV) / 256, 256, 0, stream>>>(dec_bout, out);
    prep_kernel<<<dim3(4, 32, 1), 256, 0, stream>>>(dec_W0, W0T, NIN, K0P, 16.0f);
    prep_kernel<<<dim3(32, 32, 4), 256, 0, stream>>>(dec_Wh, WhT, NH, NH, 32.0f);

    // ---- chunked 5-layer MLP, output layer fused into the last GEMM ----
    const size_t whs = (size_t)NH * NH / 2;   // fp4 bytes per hidden layer
    for (int c0 = 0; c0 < NB; c0 += Bc) {
        pe_kernel<<<(Bc * 16) / 256, 256, 0, stream>>>(coords + (size_t)c0 * NC, pe);
        gemm_kernel<0, K0P><<<8 * Mb, 256, 0, stream>>>(
            pe, W0T, bb + 0 * NH, hA, nullptr, nullptr, Mb, kw_0, ka_pe);
        gemm_kernel<0, NH><<<8 * Mb, 256, 0, stream>>>(
            hA, WhT + 0 * whs, bb + 1 * NH, hB, nullptr, nullptr, Mb, kw_h, ka_h);
        gemm_kernel<0, NH><<<8 * Mb, 256, 0, stream>>>(
            hB, WhT + 1 * whs, bb + 2 * NH, hA, nullptr, nullptr, Mb, kw_h, ka_h);
        gemm_kernel<0, NH><<<8 * Mb, 256, 0, stream>>>(
            hA, WhT + 2 * whs, bb + 3 * NH, hB, nullptr, nullptr, Mb, kw_h, ka_h);
        gemm_kernel<1, NH><<<8 * Mb, 256, 0, stream>>>(
            hB, WhT + 3 * whs, bb + 4 * NH, nullptr,
            dec_Wout, out + (size_t)c0 * NV, Mb, kw_h, ka_h);
    }
}

// Round 14
// 477.749 us; speedup vs baseline: 1.1955x; 1.1955x over previous
//
#include <hip/hip_runtime.h>
#include <hip/hip_bf16.h>
#include <stdint.h>

// ---- problem constants ----
#define NB   65536      // batch points
#define NC   2
#define NV   3
#define ND   64
#define NK   1024       // codebook entries
#define NS   4
#define NH   1024
#define NL   5
#define NF   25
#define NIN  102
#define K0P  128        // padded layer-0 K

typedef float f32x4 __attribute__((ext_vector_type(4)));
typedef int   i32x4 __attribute__((ext_vector_type(4)));
typedef int   i32x8 __attribute__((ext_vector_type(8)));
typedef unsigned char u8;
typedef unsigned int u32;

__device__ __forceinline__ void load_lds16(const void* g, void* l) {
    __builtin_amdgcn_global_load_lds(
        (const __attribute__((address_space(1))) void*)g,
        (__attribute__((address_space(3))) void*)l,
        16, 0, 0);
}

// fp8 e4m3 scalar convert (RNE, saturating): low byte of cvt_pk
__device__ __forceinline__ u8 to_fp8(float x) {
    return (u8)(__builtin_amdgcn_cvt_pk_fp8_f32(x, 0.0f, 0, false) & 0xff);
}

// ===========================================================================
// TILED OPERAND LAYOUTS (as verified in R12)
//  W_t: flat = (((bn*nIt + it)*8 + j)*2 + half)*1024 + (q*16+r16)*16 + b16
//       holds W[n][k]: n = bn*128 + j*16 + r16, k = it*128 + q*32 + half*16 + b16.
//       Per-(bn,it) slab = 16 KB contiguous -> global_load_lds staging;
//       frag ds_read = 2x b128 at stride-16 (conflict-free).
//  A_t: flat = ((m16*(K/32) + c32)*16 + r)*32 + b
//       holds A[m][k]: m = m16*16 + r, k = c32*32 + b. Direct-global frags
//       (per-lane 32B at base + lane*32: contiguous 2KB wave burst).
// ===========================================================================

// ---------------------------------------------------------------------------
// VQ kernel: single block, 1024 threads (one codebook row per thread). fp32.
// ---------------------------------------------------------------------------
__global__ __launch_bounds__(1024) void vq_kernel(
    const float* __restrict__ latents, const int* __restrict__ latent_idx,
    const float* __restrict__ codebooks, float* __restrict__ zq_out,
    float* __restrict__ out) {
    __shared__ float zcur[ND], resid[ND], zqsum[ND], ssq[ND];
    __shared__ float sDw[16];
    __shared__ int   sKw[16];
    __shared__ int   sBest;
    int t = threadIdx.x, lane = t & 63, wv = t >> 6;
    const float* img = latents + (size_t)latent_idx[0] * (NS * ND);
    if (t < ND) { resid[t] = 0.f; zqsum[t] = 0.f; }
    __syncthreads();
    float lossAcc = 0.f;   // thread 0 only
    for (int s = 0; s < NS; s++) {
        if (t < ND) {
            float iv = img[s * ND + t];
            float r  = resid[t] + iv;
            resid[t] = r;
            zcur[t]  = (s == 0) ? iv : (r - zqsum[t]);
        }
        __syncthreads();
        float zz = 0.f;
#pragma unroll
        for (int d = 0; d < ND; d++) { float z = zcur[d]; zz += z * z; }
        const float4* e4 = (const float4*)(codebooks + ((size_t)s * NK + t) * ND);
        float dot = 0.f, ee = 0.f;
#pragma unroll
        for (int i = 0; i < 16; i++) {
            float4 v = e4[i];
            dot += zcur[4 * i + 0] * v.x; dot += zcur[4 * i + 1] * v.y;
            dot += zcur[4 * i + 2] * v.z; dot += zcur[4 * i + 3] * v.w;
            ee  += v.x * v.x; ee += v.y * v.y; ee += v.z * v.z; ee += v.w * v.w;
        }
        float dmin = zz - 2.0f * dot + ee;
        int   kmin = t;
#pragma unroll
        for (int m = 1; m < 64; m <<= 1) {
            float d2 = __shfl_xor(dmin, m);
            int   k2 = __shfl_xor(kmin, m);
            if (d2 < dmin || (d2 == dmin && k2 < kmin)) { dmin = d2; kmin = k2; }
        }
        if (lane == 0) { sDw[wv] = dmin; sKw[wv] = kmin; }
        __syncthreads();
        if (t == 0) {
            float bd = sDw[0]; int bk = sKw[0];
            for (int w = 1; w < 16; w++) {
                float d2 = sDw[w]; int k2 = sKw[w];
                if (d2 < bd || (d2 == bd && k2 < bk)) { bd = d2; bk = k2; }
            }
            sBest = bk;
            out[NB * NV + s] = (float)bk;
        }
        __syncthreads();
        int best = sBest;
        const float* eb = codebooks + ((size_t)s * NK + best) * ND;
        if (t < ND) {
            float zq = eb[t];
            float d  = zq - zcur[t];
            ssq[t]   = d * d;
            zqsum[t] = zqsum[t] + (zq + (zcur[t] - zq));   // z_q_st forward (exact ref arith)
        }
        __syncthreads();
        if (t == 0) {
            float sum = 0.f;
            for (int d = 0; d < ND; d++) sum += ssq[d];
            lossAcc += 0.25f * (sum / (float)ND);
        }
    }
    if (t < ND) zq_out[t] = zqsum[t];
    if (t == 0) out[NB * NV + NS] = lossAcc;
}

// ---------------------------------------------------------------------------
// betas fused with decoder biases (fp32)
// ---------------------------------------------------------------------------
__global__ __launch_bounds__(256) void betas_kernel(
    const float* __restrict__ zq, const float* __restrict__ mod_W,
    const float* __restrict__ mod_b, const float* __restrict__ b0,
    const float* __restrict__ bh, float* __restrict__ bb) {
    int g = blockIdx.x * 256 + threadIdx.x;   // < 5120
    int l = g >> 10, n = g & 1023;
    float acc = mod_b[g];
    for (int d = 0; d < ND; d++) acc += zq[d] * mod_W[(size_t)(l * ND + d) * NH + n];
    acc += (l == 0) ? b0[n] : bh[(size_t)(l - 1) * NH + n];
    bb[g] = acc;
}

// ---------------------------------------------------------------------------
// out init: values[m][v] = bout[v] (atomic-add target for the fused layer)
// ---------------------------------------------------------------------------
__global__ __launch_bounds__(256) void init_out_kernel(
    const float* __restrict__ bout, float* __restrict__ out) {
    int g = blockIdx.x * 256 + threadIdx.x;   // < NB*NV
    out[g] = bout[g % NV];
}

// ---------------------------------------------------------------------------
// Weight prep: fp32 [Ks][1024] -> fp8 e4m3 W_t tiled (x64, undone by the
// MFMA e8m0 scale 2^-6). Zero-pad k>=Ks. nIt = Kp/128. Half-split layout.
// ---------------------------------------------------------------------------
__global__ __launch_bounds__(256) void prep_kernel(
    const float* __restrict__ src, u8* __restrict__ dst, int Ks, int Kp) {
    __shared__ float tile[32][33];
    int nIt = Kp >> 7;
    src += (size_t)blockIdx.z * Ks * NH;
    dst += (size_t)blockIdx.z * NH * Kp;
    int k0 = blockIdx.x * 32, n0 = blockIdx.y * 32;
    int tx = threadIdx.x, ty = threadIdx.y;   // (32, 8)
    for (int i = 0; i < 4; i++) {
        int k = k0 + ty + i * 8;
        int n = n0 + tx;
        tile[ty + i * 8][tx] = (k < Ks) ? src[(size_t)k * NH + n] : 0.0f;
    }
    __syncthreads();
    for (int i = 0; i < 4; i++) {
        int n = n0 + ty + i * 8;
        int k = k0 + tx;
        int bn = n >> 7, j = (n >> 4) & 7, r16 = n & 15;
        int it = k >> 7, q = (k >> 5) & 3, half = (k >> 4) & 1, b16 = k & 15;
        size_t flat = ((size_t)(((bn * nIt + it) * 8 + j) * 2 + half)) * 1024
                    + (q * 16 + r16) * 16 + b16;
        dst[flat] = to_fp8(tile[tx][ty + i * 8] * 64.0f);
    }
}

// ---------------------------------------------------------------------------
// Positional encoding -> fp8 A_t tiled [Bc][128] (K/32 = 4 chunks)
// ---------------------------------------------------------------------------
__device__ __forceinline__ float pe_val(const float* coords, int m, int k) {
    if (k < 2) return coords[m * 2 + k];
    if (k >= NIN) return 0.0f;
    int u = k - 2;
    int f = u >> 2, r = u & 3;
    float c = coords[m * 2 + (r & 1)];
    float a = c * __builtin_ldexpf(3.14159274101257324f, f);
    return (r < 2) ? sinf(a) : cosf(a);
}

__global__ __launch_bounds__(256) void pe_kernel(
    const float* __restrict__ coords, u8* __restrict__ pe) {
    int g = blockIdx.x * 256 + threadIdx.x;   // < Bc*32
    int m = g >> 5, k4 = (g & 31) * 4;
    float v0 = pe_val(coords, m, k4 + 0);
    float v1 = pe_val(coords, m, k4 + 1);
    float v2 = pe_val(coords, m, k4 + 2);
    float v3 = pe_val(coords, m, k4 + 3);
    int p = __builtin_amdgcn_cvt_pk_fp8_f32(v0, v1, 0, false);
    p     = __builtin_amdgcn_cvt_pk_fp8_f32(v2, v3, p, true);
    // A_t (K=128): flat = ((m16*4 + c32)*16 + r)*32 + b
    int m16 = m >> 4, r = m & 15, c32 = k4 >> 5, b = k4 & 31;
    *(int*)(pe + ((size_t)(m16 * 4 + c32) * 16 + r) * 32 + b) = p;
}

// ---------------------------------------------------------------------------
// MX-fp8 MFMA GEMM, R14: R12's pipelined structure with a 32m x 128n wave
// tile (128m x 128n block, 4 waves stacked in m) to raise occupancy.
// Accounting vs R12: W is shared by all 4 waves and A bytes/m-row are
// constant, so per-CU MFMA and A traffic are unchanged; only W staging
// scales with blocks/CU. acc[2][8] = 64 AGPR; A prefetch 32 VGPR; total
// ~130 regs -> __launch_bounds__(256,3) = 3 blocks/CU, 12 waves/CU (R12
// ran 2 blocks/CU / 8 waves and sat latency-bound at MfmaUtil 30%).
// W via 16KB LDS double-buffer slabs; A via register prefetch; ONE barrier
// per iter AFTER the MFMA block (R12-verified pipeline).
// MODE 0: relu(acc+bb) -> fp8, repack to next layer's A_t via LDS, coalesced.
// MODE 1: out[m][v] += relu(acc+bb).Wout[n][v], q-lane shfl + atomicAdd.
// ---------------------------------------------------------------------------
template <int MODE, int KT>
__global__ __launch_bounds__(256, 3) void gemm_kernel(
    const u8* __restrict__ A, const u8* __restrict__ W,
    const float* __restrict__ bb, u8* __restrict__ O,
    const float* __restrict__ Wout, float* __restrict__ out, int Mb) {
    __shared__ __align__(16) u8 smem[32768];
    u8* sW0 = smem;              // W buf 0 (16 KB)
    u8* sW1 = smem + 16384;      // W buf 1
    int t   = threadIdx.x;
    int fid = blockIdx.x;
    int xcd = fid & 7;
    int j8  = fid >> 3;                 // 0..Mb-1
    int bn  = j8 & 7;                   // fastest within an XCD
    int bm  = xcd * (Mb >> 3) + (j8 >> 3);
    int lane = t & 63, wm = t >> 6;     // wave owns m-slice wm*32..+31
    int q    = lane >> 4, r16 = lane & 15;
    const int nIt = KT >> 7;

    const u8* wslab = W + (size_t)(bn * nIt) * 16384;
    const u8* abase = A + ((size_t)(bm * 8 + wm * 2) * (KT >> 5)) * 512 + lane * 32;

    f32x4 acc[2][8];
    f32x4 zero = {0.f, 0.f, 0.f, 0.f};
    for (int i = 0; i < 2; i++)
        for (int j = 0; j < 8; j++) acc[i][j] = zero;

    // ---- prologue: stage W(it=0) into buf0, load A(it=0) into afc ----
#pragma unroll
    for (int p = 0; p < 4; p++) {
        int g = p * 256 + t;
        load_lds16((const void*)(wslab + g * 16), (void*)(sW0 + g * 16));
    }
    i32x8 afc[2], afn[2];
#pragma unroll
    for (int i = 0; i < 2; i++) {
        const u8* p = abase + ((size_t)i * (KT >> 5)) * 512;
        *(i32x4*)&afc[i]       = *(const i32x4*)(p);
        *((i32x4*)&afc[i] + 1) = *(const i32x4*)(p + 16);
    }
    __syncthreads();   // drains W staging + A loads

#pragma unroll 1
    for (int it = 0; it < nIt; it++) {
        u8* bufc = (it & 1) ? sW1 : sW0;
        u8* bufn = (it & 1) ? sW0 : sW1;
        // ---- issue next-iter loads FIRST (consumed after next barrier) ----
        if (it + 1 < nIt) {
            const u8* ws = wslab + (size_t)(it + 1) * 16384;
#pragma unroll
            for (int p = 0; p < 4; p++) {
                int g = p * 256 + t;
                load_lds16((const void*)(ws + g * 16), (void*)(bufn + g * 16));
            }
#pragma unroll
            for (int i = 0; i < 2; i++) {
                const u8* p = abase + ((size_t)i * (KT >> 5) + (it + 1) * 4) * 512;
                *(i32x4*)&afn[i]       = *(const i32x4*)(p);
                *((i32x4*)&afn[i] + 1) = *(const i32x4*)(p + 16);
            }
        }
        // ---- compute with current W buffer + afc ----
#pragma unroll
        for (int j = 0; j < 8; j++) {
            i32x8 bfr;
            *(i32x4*)&bfr       = *(const i32x4*)(bufc + j * 2048 + lane * 16);
            *((i32x4*)&bfr + 1) = *(const i32x4*)(bufc + j * 2048 + 1024 + lane * 16);
            // swapped operands: D rows (q*4+r) = n-dim(j), cols (r16) = m-dim(i)
#pragma unroll
            for (int i = 0; i < 2; i++)
                acc[i][j] = __builtin_amdgcn_mfma_scale_f32_16x16x128_f8f6f4(
                    bfr, afc[i], acc[i][j], 0, 0,
                    0, 0x79797979,    // scale src0 (W): 2^-6
                    0, 0x7f7f7f7f);   // scale src1 (A): 2^0
        }
        __syncthreads();   // drain: next W staged, next A landed, buf reads done
#pragma unroll
        for (int i = 0; i < 2; i++) afc[i] = afn[i];
    }

    // lane element (i,j,r): m = bm*128+wm*32+i*16+r16, n = bn*128+j*16+q*4+r
    if constexpr (MODE == 0) {
        // Repack to next layer's A_t (K=1024, 32 chunks/m16). Local LDS tile:
        // [m16_l(8)][c32_l(4)][r(16)][32B] = 16 KB.
        u8* eb = smem;
#pragma unroll
        for (int i = 0; i < 2; i++) {
#pragma unroll
            for (int j = 0; j < 8; j++) {
                int nl = j * 16 + q * 4;
                f32x4 b4 = *(const f32x4*)(bb + bn * 128 + nl);
                float v0 = fmaxf(acc[i][j][0] + b4[0], 0.0f);
                float v1 = fmaxf(acc[i][j][1] + b4[1], 0.0f);
                float v2 = fmaxf(acc[i][j][2] + b4[2], 0.0f);
                float v3 = fmaxf(acc[i][j][3] + b4[3], 0.0f);
                int p = __builtin_amdgcn_cvt_pk_fp8_f32(v0, v1, 0, false);
                p     = __builtin_amdgcn_cvt_pk_fp8_f32(v2, v3, p, true);
                int idx = (((wm * 2 + i) * 4 + (j >> 1)) * 16 + r16) * 32
                        + (j & 1) * 16 + q * 4;
                *(int*)(eb + idx) = p;
            }
        }
        __syncthreads();
        // coalesced out: 32 segments of 512B; seg = (m16_l, c32_l) ->
        // global A_t offset ((bm*8+m16_l)*32 + bn*4 + c32_l)*512
#pragma unroll
        for (int rd = 0; rd < 4; rd++) {
            int g2  = rd * 256 + t;            // dwordx4 index 0..1023
            int seg = g2 >> 5, off = (g2 & 31) * 16;
            int m16l = seg >> 2, c32l = seg & 3;
            i32x4 v = *(const i32x4*)(eb + seg * 512 + off);
            *(i32x4*)(O + ((size_t)((bm * 8 + m16l) * 32 + bn * 4 + c32l)) * 512 + off) = v;
        }
    } else {
#pragma unroll
        for (int i = 0; i < 2; i++) {
            float p0 = 0.f, p1 = 0.f, p2 = 0.f;
#pragma unroll
            for (int j = 0; j < 8; j++) {
                int nb = bn * 128 + j * 16 + q * 4;
                f32x4 b4 = *(const f32x4*)(bb + nb);
#pragma unroll
                for (int r = 0; r < 4; r++) {
                    float val = fmaxf(acc[i][j][r] + b4[r], 0.0f);
                    const float* w = Wout + (size_t)(nb + r) * NV;
                    p0 += val * w[0]; p1 += val * w[1]; p2 += val * w[2];
                }
            }
            // reduce over the 4 q-lanes (lane bits 4,5) holding the same m
            p0 += __shfl_xor(p0, 16); p0 += __shfl_xor(p0, 32);
            p1 += __shfl_xor(p1, 16); p1 += __shfl_xor(p1, 32);
            p2 += __shfl_xor(p2, 16); p2 += __shfl_xor(p2, 32);
            if (q == 0) {
                int m = bm * 128 + wm * 32 + i * 16 + r16;
                atomicAdd(&out[(size_t)m * NV + 0], p0);
                atomicAdd(&out[(size_t)m * NV + 1], p1);
                atomicAdd(&out[(size_t)m * NV + 2], p2);
            }
        }
    }
}

// ---------------------------------------------------------------------------
extern "C" void kernel_launch(void* const* d_in, const int* in_sizes, int n_in,
                              void* d_out, int out_size, void* d_ws, size_t ws_size,
                              hipStream_t stream) {
    const float* coords     = (const float*)d_in[0];
    const int*   latent_idx = (const int*)d_in[1];
    const float* latents    = (const float*)d_in[2];
    const float* codebooks  = (const float*)d_in[3];
    const float* mod_W      = (const float*)d_in[4];
    const float* mod_b      = (const float*)d_in[5];
    const float* dec_W0     = (const float*)d_in[6];
    const float* dec_b0     = (const float*)d_in[7];
    const float* dec_Wh     = (const float*)d_in[8];
    const float* dec_bh     = (const float*)d_in[9];
    const float* dec_Wout   = (const float*)d_in[10];
    const float* dec_bout   = (const float*)d_in[11];
    float* out = (float*)d_out;

    // ---- workspace layout (fixed part ~4.35 MB) ----
    char* wsb = (char*)d_ws;
    float* zq  = (float*)(wsb + 0);                        //      256 B
    float* bb  = (float*)(wsb + 256);                      //   20,480 B
    u8*    W0T = (u8*)(wsb + 20736);                       //  131,072 B  tiled
    u8*    WhT = (u8*)(wsb + 151808);                      // 4,194,304 B tiled
    const size_t fixed_end = 4346368;                      // 256-aligned

    // adaptive chunk: cap 65536 (single chunk, ws ~139 MB), halve until fits;
    // floor 2048 so Mb = Bc/128 stays a multiple of 8 (capture-safe).
    int Bc = 65536;
    while (Bc > 2048 && fixed_end + 2 * (size_t)Bc * NH > ws_size)
        Bc >>= 1;
    int Mb = Bc / 128;   // m-tiles of 128

    u8* hA = (u8*)(wsb + fixed_end);                       // [Bc][1024] fp8 A_t
    u8* hB = hA + (size_t)Bc * NH;                         // [Bc][1024] fp8 A_t
    u8* pe = hB;   // pe A_t [Bc][128] aliases hB (dead before layer-1 writes hB)

    // ---- one-time (per call) small kernels ----
    vq_kernel<<<1, 1024, 0, stream>>>(latents, latent_idx, codebooks, zq, out);
    betas_kernel<<<20, 256, 0, stream>>>(zq, mod_W, mod_b, dec_b0, dec_bh, bb);
    init_out_kernel<<<(NB * NV) / 256, 256, 0, stream>>>(dec_bout, out);
    prep_kernel<<<dim3(4, 32, 1), dim3(32, 8), 0, stream>>>(dec_W0, W0T, NIN, K0P);
    prep_kernel<<<dim3(32, 32, 4), dim3(32, 8), 0, stream>>>(dec_Wh, WhT, NH, NH);

    // ---- chunked 5-layer MLP, output layer fused into the last GEMM ----
    for (int c0 = 0; c0 < NB; c0 += Bc) {
        pe_kernel<<<(Bc * 32) / 256, 256, 0, stream>>>(coords + (size_t)c0 * NC, pe);
        gemm_kernel<0, K0P><<<8 * Mb, 256, 0, stream>>>(
            pe, W0T, bb + 0 * NH, hA, nullptr, nullptr, Mb);
        gemm_kernel<0, NH><<<8 * Mb, 256, 0, stream>>>(
            hA, WhT + 0 * (size_t)NH * NH, bb + 1 * NH, hB, nullptr, nullptr, Mb);
        gemm_kernel<0, NH><<<8 * Mb, 256, 0, stream>>>(
            hB, WhT + 1 * (size_t)NH * NH, bb + 2 * NH, hA, nullptr, nullptr, Mb);
        gemm_kernel<0, NH><<<8 * Mb, 256, 0, stream>>>(
            hA, WhT + 2 * (size_t)NH * NH, bb + 3 * NH, hB, nullptr, nullptr, Mb);
        gemm_kernel<1, NH><<<8 * Mb, 256, 0, stream>>>(
            hB, WhT + 3 * (size_t)NH * NH, bb + 4 * NH, nullptr,
            dec_Wout, out + (size_t)c0 * NV, Mb);
    }
}